// Round 4
// baseline (446.975 us; speedup 1.0000x reference)
//
#include <hip/hip_runtime.h>
#include <cstdint>

#define TT 50
#define II 5
#define PRED 12
#define SAMP 32     // samples per block
#define NSB 2       // 16-col MFMA tiles per step

typedef _Float16 f16;
typedef _Float16 f16x8 __attribute__((ext_vector_type(8)));
typedef float f32x4 __attribute__((ext_vector_type(4)));

__device__ __forceinline__ float fsig(float x) {
    return __builtin_amdgcn_rcpf(1.f + __builtin_amdgcn_exp2f(-1.4426950408889634f * x));
}
__device__ __forceinline__ float ftanh(float x) {
    return 1.f - 2.f * __builtin_amdgcn_rcpf(1.f + __builtin_amdgcn_exp2f(2.885390081777927f * x));
}

// MFMA via inline asm with VGPR-only constraints: keeps accumulators OUT of the
// AGPR file. With no AGPR usage, __launch_bounds__(512,4) (total cap 128/wave)
// leaves all 128 for arch VGPRs -> two 8-wave blocks co-resident per CU.
__device__ __forceinline__ void mfma(f32x4& d, f16x8 a, f16x8 b) {
    asm("v_mfma_f32_16x16x32_f16 %0, %1, %2, %0" : "+v"(d) : "v"(a), "v"(b));
}

// A-fragments: tile (w,gs) row r holds gate-row gw = gs*128 + w*16 + r.
// Lane (q,cl) element j of wr[gs][kc] = Wcat[gw(cl)][k = kc*32 + q*8 + j]:
//   kc<4 -> Whh[gw][k]; kc=4 (only q==0 nonzero): j<5 Wih[gw][j], j==5 bih+bhh, else 0.
// MFMA C layout (col=cl, row=q*4+idx) gives acc[gs][idx] = gate gs of unit
//   jb+idx (jb = w*16 + q*4), sample ns*16+cl.  One B-read feeds 4 MFMAs.
__device__ __forceinline__ void load_frags(const float* __restrict__ Wih,
                                           const float* __restrict__ Whh,
                                           const float* __restrict__ bih,
                                           const float* __restrict__ bhh,
                                           int w, int q, int cl, f16x8 wr[4][5]) {
    #pragma unroll
    for (int gs = 0; gs < 4; ++gs) {
        const int gw = gs * 128 + w * 16 + cl;
        const float* whr = Whh + gw * 128 + q * 8;
        #pragma unroll
        for (int kc = 0; kc < 4; ++kc) {
            f32x4 a = *(const f32x4*)(whr + kc * 32);
            f32x4 b = *(const f32x4*)(whr + kc * 32 + 4);
            f16x8 f;
            f[0] = (f16)a[0]; f[1] = (f16)a[1]; f[2] = (f16)a[2]; f[3] = (f16)a[3];
            f[4] = (f16)b[0]; f[5] = (f16)b[1]; f[6] = (f16)b[2]; f[7] = (f16)b[3];
            wr[gs][kc] = f;
        }
        f16x8 f;
        #pragma unroll
        for (int j = 0; j < 8; ++j) f[j] = (f16)0.f;
        if (q == 0) {
            f[0] = (f16)Wih[gw * 5 + 0]; f[1] = (f16)Wih[gw * 5 + 1];
            f[2] = (f16)Wih[gw * 5 + 2]; f[3] = (f16)Wih[gw * 5 + 3];
            f[4] = (f16)Wih[gw * 5 + 4];
            f[5] = (f16)(bih[gw] + bhh[gw]);
        }
        wr[gs][4] = f;
    }
}

// 512 blocks x 512 threads (8 waves), 32 samples/block -> TWO blocks per CU.
// Co-resident blocks drift out of phase: one block's MFMA overlaps the other's
// transcendental phase, and barrier-wait is covered by the sibling block.
// State: double-buffered h rows, 256 B/row (16 chunks), chunk swizzle
// phys = logical ^ fswz(row&15), fswz(c) = 2*(c&7) | (c>>3).
// Encoder: ONE barrier/step. Decoder: two (predpart reduction).
__global__ __launch_bounds__(512, 4)
void lstm_kernel(const float* __restrict__ x,
                 const float* __restrict__ eWih, const float* __restrict__ eWhh,
                 const float* __restrict__ ebih, const float* __restrict__ ebhh,
                 const float* __restrict__ dWih, const float* __restrict__ dWhh,
                 const float* __restrict__ dbih, const float* __restrict__ dbhh,
                 const float* __restrict__ linW, const float* __restrict__ linB,
                 float* __restrict__ out) {
    __shared__ __align__(16) unsigned char state[2 * SAMP * 256];   // 16 KB
    __shared__ __align__(16) f16 xstage[52 * SAMP * 8];             // 26 KB
    __shared__ float predpart[8][SAMP][2];                          // 2 KB

    const int tid  = threadIdx.x;
    const int lane = tid & 63;
    const int w    = tid >> 6;       // wave 0..7
    const int q    = lane >> 4;      // 0..3
    const int cl   = lane & 15;      // 0..15
    const int s0   = blockIdx.x * SAMP;
    const int jb   = w * 16 + q * 4;                 // this lane's hidden-unit base
    const int fswz = (2 * (cl & 7)) | (cl >> 3);     // bijective 0..15

    // per-lane LDS byte offsets (within one state buffer, before +ns*4096)
    int hro[4];
    #pragma unroll
    for (int kc = 0; kc < 4; ++kc)
        hro[kc] = cl * 256 + (((kc * 4 + q) ^ fswz) & 15) * 16;
    const int physh = ((jb >> 3) ^ fswz) & 15;
    const int hwo   = cl * 256 + physh * 16 + (jb & 7) * 2;

    // ---- init: zero state buffer 0 (h0 = 0), stage all x as f16 rows ----
    {
        uint32_t* sp = (uint32_t*)state;
        #pragma unroll
        for (int r = 0; r < 4; ++r) sp[tid + r * 512] = 0u;   // 8192 B = buffer 0
    }
    #pragma unroll
    for (int k = 0; k < 4; ++k) {
        int c = tid + k * 512;
        if (c < TT * SAMP) {
            int t = c >> 5, s = c & 31;
            const float* xr = x + (size_t)(s0 + s) * (TT * II) + t * II;
            union { f16 h[8]; uint4 u; } pk;
            pk.h[0] = (f16)xr[0]; pk.h[1] = (f16)xr[1]; pk.h[2] = (f16)xr[2];
            pk.h[3] = (f16)xr[3]; pk.h[4] = (f16)xr[4];
            pk.h[5] = (f16)1.f;  pk.h[6] = (f16)0.f;  pk.h[7] = (f16)0.f;
            *(uint4*)(xstage + (t * SAMP + s) * 8) = pk.u;
        }
    }

    f16x8 wr[4][5];
    load_frags(eWih, eWhh, ebih, ebhh, w, q, cl, wr);

    float creg[NSB][4];
    #pragma unroll
    for (int ns = 0; ns < NSB; ++ns)
        #pragma unroll
        for (int i = 0; i < 4; ++i) creg[ns][i] = 0.f;

    __syncthreads();

    // ===================== encoder: 1 barrier/step =====================
    #pragma unroll 1
    for (int t = 0; t < TT; ++t) {
        const int curoff = (t & 1) << 13;        // *8192
        const int nxtoff = curoff ^ 8192;
        #pragma unroll
        for (int ns = 0; ns < NSB; ++ns) {
            const unsigned char* cb = state + curoff + ns * 4096;
            f16x8 bx = *(const f16x8*)(xstage + (t * SAMP + ns * 16 + cl) * 8);
            f16x8 b0 = *(const f16x8*)(cb + hro[0]);
            f32x4 a0 = {0.f, 0.f, 0.f, 0.f};
            f32x4 a1 = {0.f, 0.f, 0.f, 0.f};
            f32x4 a2 = {0.f, 0.f, 0.f, 0.f};
            f32x4 a3 = {0.f, 0.f, 0.f, 0.f};
            mfma(a0, wr[0][0], b0);
            mfma(a1, wr[1][0], b0);
            mfma(a2, wr[2][0], b0);
            mfma(a3, wr[3][0], b0);
            #pragma unroll
            for (int kc = 1; kc < 4; ++kc) {
                f16x8 bh = *(const f16x8*)(cb + hro[kc]);
                mfma(a0, wr[0][kc], bh);
                mfma(a1, wr[1][kc], bh);
                mfma(a2, wr[2][kc], bh);
                mfma(a3, wr[3][kc], bh);
            }
            mfma(a0, wr[0][4], bx);
            mfma(a1, wr[1][4], bx);
            mfma(a2, wr[2][4], bx);
            mfma(a3, wr[3][4], bx);

            // acc[gs][idx] = gate gs of unit jb+idx, sample ns*16+cl
            union { f16 h[4]; uint2 u; } pk;
            #pragma unroll
            for (int idx = 0; idx < 4; ++idx) {
                float ii = fsig(a0[idx]);
                float ff = fsig(a1[idx]);
                float gg = ftanh(a2[idx]);
                float oo = fsig(a3[idx]);
                float cn = ff * creg[ns][idx] + ii * gg;
                creg[ns][idx] = cn;
                pk.h[idx] = (f16)(oo * ftanh(cn));
            }
            *(uint2*)(state + nxtoff + ns * 4096 + hwo) = pk.u;
        }
        __syncthreads();   // writes to nxt visible; cur reads done
    }

    // decoder weights + decoder-only registers (loaded late; lin weights f16-packed)
    load_frags(dWih, dWhh, dbih, dbhh, w, q, cl, wr);
    f16 w0h[4], w1h[4];
    #pragma unroll
    for (int idx = 0; idx < 4; ++idx) {
        w0h[idx] = (f16)linW[jb + idx];
        w1h[idx] = (f16)linW[128 + jb + idx];
    }
    float sc0 = 0.f, sc1 = 0.f, sc2 = 0.f, lb0 = 0.f, lb1 = 0.f;
    if (tid < SAMP) {
        const float* xr = x + (size_t)(s0 + tid) * (TT * II) + 49 * II;
        sc0 = xr[2]; sc1 = xr[3]; sc2 = xr[4];
        lb0 = linB[0]; lb1 = linB[1];
    }

    // ===================== decoder =====================
    // after 50 encoder steps h lives in buf0; dec_in0 = x[49] row already in xstage
    #pragma unroll 1
    for (int td = 0; td < PRED; ++td) {
        const int curoff = (td & 1) << 13;
        const int nxtoff = curoff ^ 8192;
        const int xslot  = (td == 0) ? 49 : (50 + (td & 1));
        float p0s[NSB], p1s[NSB];
        #pragma unroll
        for (int ns = 0; ns < NSB; ++ns) {
            const unsigned char* cb = state + curoff + ns * 4096;
            f16x8 bx = *(const f16x8*)(xstage + (xslot * SAMP + ns * 16 + cl) * 8);
            f16x8 b0 = *(const f16x8*)(cb + hro[0]);
            f32x4 a0 = {0.f, 0.f, 0.f, 0.f};
            f32x4 a1 = {0.f, 0.f, 0.f, 0.f};
            f32x4 a2 = {0.f, 0.f, 0.f, 0.f};
            f32x4 a3 = {0.f, 0.f, 0.f, 0.f};
            mfma(a0, wr[0][0], b0);
            mfma(a1, wr[1][0], b0);
            mfma(a2, wr[2][0], b0);
            mfma(a3, wr[3][0], b0);
            #pragma unroll
            for (int kc = 1; kc < 4; ++kc) {
                f16x8 bh = *(const f16x8*)(cb + hro[kc]);
                mfma(a0, wr[0][kc], bh);
                mfma(a1, wr[1][kc], bh);
                mfma(a2, wr[2][kc], bh);
                mfma(a3, wr[3][kc], bh);
            }
            mfma(a0, wr[0][4], bx);
            mfma(a1, wr[1][4], bx);
            mfma(a2, wr[2][4], bx);
            mfma(a3, wr[3][4], bx);

            float p0 = 0.f, p1 = 0.f;
            union { f16 h[4]; uint2 u; } pk;
            #pragma unroll
            for (int idx = 0; idx < 4; ++idx) {
                float ii = fsig(a0[idx]);
                float ff = fsig(a1[idx]);
                float gg = ftanh(a2[idx]);
                float oo = fsig(a3[idx]);
                float cn = ff * creg[ns][idx] + ii * gg;
                creg[ns][idx] = cn;
                float hv = oo * ftanh(cn);
                p0 += hv * (float)w0h[idx];
                p1 += hv * (float)w1h[idx];
                pk.h[idx] = (f16)hv;
            }
            *(uint2*)(state + nxtoff + ns * 4096 + hwo) = pk.u;
            p0 += __shfl_xor(p0, 16); p0 += __shfl_xor(p0, 32);
            p1 += __shfl_xor(p1, 16); p1 += __shfl_xor(p1, 32);
            p0s[ns] = p0; p1s[ns] = p1;
        }
        if (q == 0) {
            #pragma unroll
            for (int ns = 0; ns < NSB; ++ns) {
                predpart[w][ns * 16 + cl][0] = p0s[ns];
                predpart[w][ns * 16 + cl][1] = p1s[ns];
            }
        }
        __syncthreads();   // A: predpart ready, state reads done
        if (tid < SAMP) {
            float a0 = lb0, a1 = lb1;
            #pragma unroll
            for (int ww = 0; ww < 8; ++ww) {
                a0 += predpart[ww][tid][0];
                a1 += predpart[ww][tid][1];
            }
            float2 o2; o2.x = a0; o2.y = a1;
            *(float2*)(out + (size_t)(s0 + tid) * (PRED * 2) + td * 2) = o2;
            union { f16 h[8]; uint4 u; } pk;
            pk.h[0] = (f16)a0;  pk.h[1] = (f16)a1;
            pk.h[2] = (f16)sc0; pk.h[3] = (f16)sc1; pk.h[4] = (f16)sc2;
            pk.h[5] = (f16)1.f; pk.h[6] = (f16)0.f; pk.h[7] = (f16)0.f;
            int ws = 50 + ((td + 1) & 1);
            *(uint4*)(xstage + (ws * SAMP + tid) * 8) = pk.u;   // next dec_in
        }
        __syncthreads();   // B: dec_in visible
    }
}

extern "C" void kernel_launch(void* const* d_in, const int* in_sizes, int n_in,
                              void* d_out, int out_size, void* d_ws, size_t ws_size,
                              hipStream_t stream) {
    (void)in_sizes; (void)n_in; (void)out_size; (void)d_ws; (void)ws_size;
    const float* x    = (const float*)d_in[0];
    const float* eWih = (const float*)d_in[1];
    const float* eWhh = (const float*)d_in[2];
    const float* ebih = (const float*)d_in[3];
    const float* ebhh = (const float*)d_in[4];
    const float* dWih = (const float*)d_in[5];
    const float* dWhh = (const float*)d_in[6];
    const float* dbih = (const float*)d_in[7];
    const float* dbhh = (const float*)d_in[8];
    const float* linW = (const float*)d_in[9];
    const float* linB = (const float*)d_in[10];

    lstm_kernel<<<512, 512, 0, stream>>>(x, eWih, eWhh, ebih, ebhh,
                                         dWih, dWhh, dbih, dbhh,
                                         linW, linB, (float*)d_out);
}

// Round 5
// 311.194 us; speedup vs baseline: 1.4363x; 1.4363x over previous
//
#include <hip/hip_runtime.h>
#include <cstdint>

#define TT 50
#define II 5
#define PRED 12
#define SAMP 32     // samples per block
#define NSB 2       // 16-col MFMA tiles per step

typedef _Float16 f16;
typedef _Float16 f16x8 __attribute__((ext_vector_type(8)));
typedef float f32x4 __attribute__((ext_vector_type(4)));

__device__ __forceinline__ float fsig(float x) {
    return __builtin_amdgcn_rcpf(1.f + __builtin_amdgcn_exp2f(-1.4426950408889634f * x));
}
__device__ __forceinline__ float ftanh(float x) {
    return 1.f - 2.f * __builtin_amdgcn_rcpf(1.f + __builtin_amdgcn_exp2f(2.885390081777927f * x));
}

// MFMA via inline asm with VGPR-only constraints: keeps accumulators OUT of the
// AGPR file so the hardware arch+acc total stays <= 128/wave.
// __launch_bounds__ 2nd arg is CUDA-style min BLOCKS/CU on this toolchain
// (measured r1/r3/r4): (512,2) -> 16 waves/CU -> 128-reg cap, no spill.
__device__ __forceinline__ void mfma(f32x4& d, f16x8 a, f16x8 b) {
    asm("v_mfma_f32_16x16x32_f16 %0, %1, %2, %0" : "+v"(d) : "v"(a), "v"(b));
}

// A-fragments: tile (w,gs) row r holds gate-row gw = gs*128 + w*16 + r.
// Lane (q,cl) element j of wr[gs][kc] = Wcat[gw(cl)][k = kc*32 + q*8 + j]:
//   kc<4 -> Whh[gw][k]; kc=4 (only q==0 nonzero): j<5 Wih[gw][j], j==5 bih+bhh, else 0.
// MFMA C layout (col=cl, row=q*4+idx) gives acc[gs][idx] = gate gs of unit
//   jb+idx (jb = w*16 + q*4), sample ns*16+cl.  One B-read feeds 4 MFMAs.
__device__ __forceinline__ void load_frags(const float* __restrict__ Wih,
                                           const float* __restrict__ Whh,
                                           const float* __restrict__ bih,
                                           const float* __restrict__ bhh,
                                           int w, int q, int cl, f16x8 wr[4][5]) {
    #pragma unroll
    for (int gs = 0; gs < 4; ++gs) {
        const int gw = gs * 128 + w * 16 + cl;
        const float* whr = Whh + gw * 128 + q * 8;
        #pragma unroll
        for (int kc = 0; kc < 4; ++kc) {
            f32x4 a = *(const f32x4*)(whr + kc * 32);
            f32x4 b = *(const f32x4*)(whr + kc * 32 + 4);
            f16x8 f;
            f[0] = (f16)a[0]; f[1] = (f16)a[1]; f[2] = (f16)a[2]; f[3] = (f16)a[3];
            f[4] = (f16)b[0]; f[5] = (f16)b[1]; f[6] = (f16)b[2]; f[7] = (f16)b[3];
            wr[gs][kc] = f;
        }
        f16x8 f;
        #pragma unroll
        for (int j = 0; j < 8; ++j) f[j] = (f16)0.f;
        if (q == 0) {
            f[0] = (f16)Wih[gw * 5 + 0]; f[1] = (f16)Wih[gw * 5 + 1];
            f[2] = (f16)Wih[gw * 5 + 2]; f[3] = (f16)Wih[gw * 5 + 3];
            f[4] = (f16)Wih[gw * 5 + 4];
            f[5] = (f16)(bih[gw] + bhh[gw]);
        }
        wr[gs][4] = f;
    }
}

// 512 blocks x 512 threads (8 waves), 32 samples/block -> TWO blocks per CU.
// Co-resident blocks drift out of phase: one block's MFMA overlaps the other's
// transcendental phase, and barrier-wait is covered by the sibling block.
// State: double-buffered h rows, 256 B/row (16 chunks), chunk swizzle
// phys = logical ^ fswz(row&15), fswz(c) = 2*(c&7) | (c>>3).
// Encoder: ONE barrier/step. Decoder: two (predpart reduction).
__global__ __launch_bounds__(512, 2)
void lstm_kernel(const float* __restrict__ x,
                 const float* __restrict__ eWih, const float* __restrict__ eWhh,
                 const float* __restrict__ ebih, const float* __restrict__ ebhh,
                 const float* __restrict__ dWih, const float* __restrict__ dWhh,
                 const float* __restrict__ dbih, const float* __restrict__ dbhh,
                 const float* __restrict__ linW, const float* __restrict__ linB,
                 float* __restrict__ out) {
    __shared__ __align__(16) unsigned char state[2 * SAMP * 256];   // 16 KB
    __shared__ __align__(16) f16 xstage[52 * SAMP * 8];             // 26 KB
    __shared__ float predpart[8][SAMP][2];                          // 2 KB

    const int tid  = threadIdx.x;
    const int lane = tid & 63;
    const int w    = tid >> 6;       // wave 0..7
    const int q    = lane >> 4;      // 0..3
    const int cl   = lane & 15;      // 0..15
    const int s0   = blockIdx.x * SAMP;
    const int jb   = w * 16 + q * 4;                 // this lane's hidden-unit base
    const int fswz = (2 * (cl & 7)) | (cl >> 3);     // bijective 0..15

    // per-lane LDS byte offsets (within one state buffer, before +ns*4096)
    int hro[4];
    #pragma unroll
    for (int kc = 0; kc < 4; ++kc)
        hro[kc] = cl * 256 + (((kc * 4 + q) ^ fswz) & 15) * 16;
    const int physh = ((jb >> 3) ^ fswz) & 15;
    const int hwo   = cl * 256 + physh * 16 + (jb & 7) * 2;

    // ---- init: zero state buffer 0 (h0 = 0), stage all x as f16 rows ----
    {
        uint32_t* sp = (uint32_t*)state;
        #pragma unroll
        for (int r = 0; r < 4; ++r) sp[tid + r * 512] = 0u;   // 8192 B = buffer 0
    }
    #pragma unroll
    for (int k = 0; k < 4; ++k) {
        int c = tid + k * 512;
        if (c < TT * SAMP) {
            int t = c >> 5, s = c & 31;
            const float* xr = x + (size_t)(s0 + s) * (TT * II) + t * II;
            union { f16 h[8]; uint4 u; } pk;
            pk.h[0] = (f16)xr[0]; pk.h[1] = (f16)xr[1]; pk.h[2] = (f16)xr[2];
            pk.h[3] = (f16)xr[3]; pk.h[4] = (f16)xr[4];
            pk.h[5] = (f16)1.f;  pk.h[6] = (f16)0.f;  pk.h[7] = (f16)0.f;
            *(uint4*)(xstage + (t * SAMP + s) * 8) = pk.u;
        }
    }

    f16x8 wr[4][5];
    load_frags(eWih, eWhh, ebih, ebhh, w, q, cl, wr);

    float creg[NSB][4];
    #pragma unroll
    for (int ns = 0; ns < NSB; ++ns)
        #pragma unroll
        for (int i = 0; i < 4; ++i) creg[ns][i] = 0.f;

    __syncthreads();

    // ===================== encoder: 1 barrier/step =====================
    #pragma unroll 1
    for (int t = 0; t < TT; ++t) {
        const int curoff = (t & 1) << 13;        // *8192
        const int nxtoff = curoff ^ 8192;
        #pragma unroll
        for (int ns = 0; ns < NSB; ++ns) {
            const unsigned char* cb = state + curoff + ns * 4096;
            f16x8 bx = *(const f16x8*)(xstage + (t * SAMP + ns * 16 + cl) * 8);
            f16x8 b0 = *(const f16x8*)(cb + hro[0]);
            f32x4 a0 = {0.f, 0.f, 0.f, 0.f};
            f32x4 a1 = {0.f, 0.f, 0.f, 0.f};
            f32x4 a2 = {0.f, 0.f, 0.f, 0.f};
            f32x4 a3 = {0.f, 0.f, 0.f, 0.f};
            mfma(a0, wr[0][0], b0);
            mfma(a1, wr[1][0], b0);
            mfma(a2, wr[2][0], b0);
            mfma(a3, wr[3][0], b0);
            #pragma unroll
            for (int kc = 1; kc < 4; ++kc) {
                f16x8 bh = *(const f16x8*)(cb + hro[kc]);
                mfma(a0, wr[0][kc], bh);
                mfma(a1, wr[1][kc], bh);
                mfma(a2, wr[2][kc], bh);
                mfma(a3, wr[3][kc], bh);
            }
            mfma(a0, wr[0][4], bx);
            mfma(a1, wr[1][4], bx);
            mfma(a2, wr[2][4], bx);
            mfma(a3, wr[3][4], bx);

            // acc[gs][idx] = gate gs of unit jb+idx, sample ns*16+cl
            union { f16 h[4]; uint2 u; } pk;
            #pragma unroll
            for (int idx = 0; idx < 4; ++idx) {
                float ii = fsig(a0[idx]);
                float ff = fsig(a1[idx]);
                float gg = ftanh(a2[idx]);
                float oo = fsig(a3[idx]);
                float cn = ff * creg[ns][idx] + ii * gg;
                creg[ns][idx] = cn;
                pk.h[idx] = (f16)(oo * ftanh(cn));
            }
            *(uint2*)(state + nxtoff + ns * 4096 + hwo) = pk.u;
        }
        __syncthreads();   // writes to nxt visible; cur reads done
    }

    // decoder weights + decoder-only registers (loaded late; lin weights f16-packed)
    load_frags(dWih, dWhh, dbih, dbhh, w, q, cl, wr);
    f16 w0h[4], w1h[4];
    #pragma unroll
    for (int idx = 0; idx < 4; ++idx) {
        w0h[idx] = (f16)linW[jb + idx];
        w1h[idx] = (f16)linW[128 + jb + idx];
    }
    float sc0 = 0.f, sc1 = 0.f, sc2 = 0.f, lb0 = 0.f, lb1 = 0.f;
    if (tid < SAMP) {
        const float* xr = x + (size_t)(s0 + tid) * (TT * II) + 49 * II;
        sc0 = xr[2]; sc1 = xr[3]; sc2 = xr[4];
        lb0 = linB[0]; lb1 = linB[1];
    }

    // ===================== decoder =====================
    // after 50 encoder steps h lives in buf0; dec_in0 = x[49] row already in xstage
    #pragma unroll 1
    for (int td = 0; td < PRED; ++td) {
        const int curoff = (td & 1) << 13;
        const int nxtoff = curoff ^ 8192;
        const int xslot  = (td == 0) ? 49 : (50 + (td & 1));
        float p0s[NSB], p1s[NSB];
        #pragma unroll
        for (int ns = 0; ns < NSB; ++ns) {
            const unsigned char* cb = state + curoff + ns * 4096;
            f16x8 bx = *(const f16x8*)(xstage + (xslot * SAMP + ns * 16 + cl) * 8);
            f16x8 b0 = *(const f16x8*)(cb + hro[0]);
            f32x4 a0 = {0.f, 0.f, 0.f, 0.f};
            f32x4 a1 = {0.f, 0.f, 0.f, 0.f};
            f32x4 a2 = {0.f, 0.f, 0.f, 0.f};
            f32x4 a3 = {0.f, 0.f, 0.f, 0.f};
            mfma(a0, wr[0][0], b0);
            mfma(a1, wr[1][0], b0);
            mfma(a2, wr[2][0], b0);
            mfma(a3, wr[3][0], b0);
            #pragma unroll
            for (int kc = 1; kc < 4; ++kc) {
                f16x8 bh = *(const f16x8*)(cb + hro[kc]);
                mfma(a0, wr[0][kc], bh);
                mfma(a1, wr[1][kc], bh);
                mfma(a2, wr[2][kc], bh);
                mfma(a3, wr[3][kc], bh);
            }
            mfma(a0, wr[0][4], bx);
            mfma(a1, wr[1][4], bx);
            mfma(a2, wr[2][4], bx);
            mfma(a3, wr[3][4], bx);

            float p0 = 0.f, p1 = 0.f;
            union { f16 h[4]; uint2 u; } pk;
            #pragma unroll
            for (int idx = 0; idx < 4; ++idx) {
                float ii = fsig(a0[idx]);
                float ff = fsig(a1[idx]);
                float gg = ftanh(a2[idx]);
                float oo = fsig(a3[idx]);
                float cn = ff * creg[ns][idx] + ii * gg;
                creg[ns][idx] = cn;
                float hv = oo * ftanh(cn);
                p0 += hv * (float)w0h[idx];
                p1 += hv * (float)w1h[idx];
                pk.h[idx] = (f16)hv;
            }
            *(uint2*)(state + nxtoff + ns * 4096 + hwo) = pk.u;
            p0 += __shfl_xor(p0, 16); p0 += __shfl_xor(p0, 32);
            p1 += __shfl_xor(p1, 16); p1 += __shfl_xor(p1, 32);
            p0s[ns] = p0; p1s[ns] = p1;
        }
        if (q == 0) {
            #pragma unroll
            for (int ns = 0; ns < NSB; ++ns) {
                predpart[w][ns * 16 + cl][0] = p0s[ns];
                predpart[w][ns * 16 + cl][1] = p1s[ns];
            }
        }
        __syncthreads();   // A: predpart ready, state reads done
        if (tid < SAMP) {
            float a0 = lb0, a1 = lb1;
            #pragma unroll
            for (int ww = 0; ww < 8; ++ww) {
                a0 += predpart[ww][tid][0];
                a1 += predpart[ww][tid][1];
            }
            float2 o2; o2.x = a0; o2.y = a1;
            *(float2*)(out + (size_t)(s0 + tid) * (PRED * 2) + td * 2) = o2;
            union { f16 h[8]; uint4 u; } pk;
            pk.h[0] = (f16)a0;  pk.h[1] = (f16)a1;
            pk.h[2] = (f16)sc0; pk.h[3] = (f16)sc1; pk.h[4] = (f16)sc2;
            pk.h[5] = (f16)1.f; pk.h[6] = (f16)0.f; pk.h[7] = (f16)0.f;
            int ws = 50 + ((td + 1) & 1);
            *(uint4*)(xstage + (ws * SAMP + tid) * 8) = pk.u;   // next dec_in
        }
        __syncthreads();   // B: dec_in visible
    }
}

extern "C" void kernel_launch(void* const* d_in, const int* in_sizes, int n_in,
                              void* d_out, int out_size, void* d_ws, size_t ws_size,
                              hipStream_t stream) {
    (void)in_sizes; (void)n_in; (void)out_size; (void)d_ws; (void)ws_size;
    const float* x    = (const float*)d_in[0];
    const float* eWih = (const float*)d_in[1];
    const float* eWhh = (const float*)d_in[2];
    const float* ebih = (const float*)d_in[3];
    const float* ebhh = (const float*)d_in[4];
    const float* dWih = (const float*)d_in[5];
    const float* dWhh = (const float*)d_in[6];
    const float* dbih = (const float*)d_in[7];
    const float* dbhh = (const float*)d_in[8];
    const float* linW = (const float*)d_in[9];
    const float* linB = (const float*)d_in[10];

    lstm_kernel<<<512, 512, 0, stream>>>(x, eWih, eWhh, ebih, ebhh,
                                         dWih, dWhh, dbih, dbhh,
                                         linW, linB, (float*)d_out);
}

// Round 7
// 284.693 us; speedup vs baseline: 1.5700x; 1.0931x over previous
//
#include <hip/hip_runtime.h>
#include <cstdint>

#define TT 50
#define II 5
#define PRED 12

typedef _Float16 f16;
typedef _Float16 f16x8 __attribute__((ext_vector_type(8)));
typedef float f32x4 __attribute__((ext_vector_type(4)));

__device__ __forceinline__ float fsig(float x) {
    return __builtin_amdgcn_rcpf(1.f + __builtin_amdgcn_exp2f(-1.4426950408889634f * x));
}
__device__ __forceinline__ float ftanh(float x) {
    return 1.f - 2.f * __builtin_amdgcn_rcpf(1.f + __builtin_amdgcn_exp2f(2.885390081777927f * x));
}

// A-fragments: tile (w,gs) row r holds gate-row gw = gs*128 + w*16 + r.
// Lane (q,cl) element j of wr[gs][kc] = Wcat[gw(cl)][k = kc*32 + q*8 + j]:
//   kc<4 -> Whh[gw][k]; kc=4 (only q==0 nonzero): j<5 Wih[gw][j], j==5 bih+bhh, else 0.
// MFMA C layout (col=cl, row=q*4+idx) gives acc[gs][idx] = gate gs of unit
//   jb+idx (jb = w*16 + q*4), sample ns*16+cl.
__device__ __forceinline__ void load_frags(const float* __restrict__ Wih,
                                           const float* __restrict__ Whh,
                                           const float* __restrict__ bih,
                                           const float* __restrict__ bhh,
                                           int w, int q, int cl, f16x8 wr[4][5]) {
    #pragma unroll
    for (int gs = 0; gs < 4; ++gs) {
        const int gw = gs * 128 + w * 16 + cl;
        const float* whr = Whh + gw * 128 + q * 8;
        #pragma unroll
        for (int kc = 0; kc < 4; ++kc) {
            f32x4 a = *(const f32x4*)(whr + kc * 32);
            f32x4 b = *(const f32x4*)(whr + kc * 32 + 4);
            f16x8 f;
            f[0] = (f16)a[0]; f[1] = (f16)a[1]; f[2] = (f16)a[2]; f[3] = (f16)a[3];
            f[4] = (f16)b[0]; f[5] = (f16)b[1]; f[6] = (f16)b[2]; f[7] = (f16)b[3];
            wr[gs][kc] = f;
        }
        f16x8 f;
        #pragma unroll
        for (int j = 0; j < 8; ++j) f[j] = (f16)0.f;
        if (q == 0) {
            f[0] = (f16)Wih[gw * 5 + 0]; f[1] = (f16)Wih[gw * 5 + 1];
            f[2] = (f16)Wih[gw * 5 + 2]; f[3] = (f16)Wih[gw * 5 + 3];
            f[4] = (f16)Wih[gw * 5 + 4];
            f[5] = (f16)(bih[gw] + bhh[gw]);
        }
        wr[gs][4] = f;
    }
}

// Intrinsic MFMA: compiler handles all MAI hazards (r6's raw-asm "a"-constraint
// version NaN'd -- v_accvgpr_write -> asm-MFMA srcA needs manual wait states the
// backend can't insert around opaque inline asm). Accumulators land in AGPRs.
__device__ __forceinline__ void mfma_group(f32x4 (&acc)[4][2],
        const unsigned char* hb, const f16* xrow,
        const f16x8 (&wr)[4][5],
        const int (&hro)[4], int cl) {
    const f32x4 z4 = {0.f, 0.f, 0.f, 0.f};
    #pragma unroll
    for (int ns = 0; ns < 2; ++ns) {
        const unsigned char* cb = hb + ns * 4096;
        f16x8 bx = *(const f16x8*)(xrow + (ns * 16 + cl) * 8);
        f16x8 b0 = *(const f16x8*)(cb + hro[0]);
        acc[0][ns] = __builtin_amdgcn_mfma_f32_16x16x32_f16(wr[0][0], b0, z4, 0, 0, 0);
        acc[1][ns] = __builtin_amdgcn_mfma_f32_16x16x32_f16(wr[1][0], b0, z4, 0, 0, 0);
        acc[2][ns] = __builtin_amdgcn_mfma_f32_16x16x32_f16(wr[2][0], b0, z4, 0, 0, 0);
        acc[3][ns] = __builtin_amdgcn_mfma_f32_16x16x32_f16(wr[3][0], b0, z4, 0, 0, 0);
        #pragma unroll
        for (int kc = 1; kc < 4; ++kc) {
            f16x8 bh = *(const f16x8*)(cb + hro[kc]);
            acc[0][ns] = __builtin_amdgcn_mfma_f32_16x16x32_f16(wr[0][kc], bh, acc[0][ns], 0, 0, 0);
            acc[1][ns] = __builtin_amdgcn_mfma_f32_16x16x32_f16(wr[1][kc], bh, acc[1][ns], 0, 0, 0);
            acc[2][ns] = __builtin_amdgcn_mfma_f32_16x16x32_f16(wr[2][kc], bh, acc[2][ns], 0, 0, 0);
            acc[3][ns] = __builtin_amdgcn_mfma_f32_16x16x32_f16(wr[3][kc], bh, acc[3][ns], 0, 0, 0);
        }
        acc[0][ns] = __builtin_amdgcn_mfma_f32_16x16x32_f16(wr[0][4], bx, acc[0][ns], 0, 0, 0);
        acc[1][ns] = __builtin_amdgcn_mfma_f32_16x16x32_f16(wr[1][4], bx, acc[1][ns], 0, 0, 0);
        acc[2][ns] = __builtin_amdgcn_mfma_f32_16x16x32_f16(wr[2][4], bx, acc[2][ns], 0, 0, 0);
        acc[3][ns] = __builtin_amdgcn_mfma_f32_16x16x32_f16(wr[3][4], bx, acc[3][ns], 0, 0, 0);
    }
}

__device__ __forceinline__ void valu_enc(f32x4 (&acc)[4][2], float (&cr)[2][4],
        unsigned char* hb, int hwo) {
    #pragma unroll
    for (int ns = 0; ns < 2; ++ns) {
        union { f16 h[4]; uint2 u; } pk;
        #pragma unroll
        for (int idx = 0; idx < 4; ++idx) {
            float ii = fsig(acc[0][ns][idx]);
            float ff = fsig(acc[1][ns][idx]);
            float gg = ftanh(acc[2][ns][idx]);
            float oo = fsig(acc[3][ns][idx]);
            float cn = ff * cr[ns][idx] + ii * gg;
            cr[ns][idx] = cn;
            pk.h[idx] = (f16)(oo * ftanh(cn));
        }
        *(uint2*)(hb + ns * 4096 + hwo) = pk.u;
    }
}

__device__ __forceinline__ void valu_dec(f32x4 (&acc)[4][2], float (&cr)[2][4],
        unsigned char* hb, int hwo,
        const f16 (&w0h)[4], const f16 (&w1h)[4],
        float (*pp)[32][2], int w, int q, int cl) {
    #pragma unroll
    for (int ns = 0; ns < 2; ++ns) {
        union { f16 h[4]; uint2 u; } pk;
        float p0 = 0.f, p1 = 0.f;
        #pragma unroll
        for (int idx = 0; idx < 4; ++idx) {
            float ii = fsig(acc[0][ns][idx]);
            float ff = fsig(acc[1][ns][idx]);
            float gg = ftanh(acc[2][ns][idx]);
            float oo = fsig(acc[3][ns][idx]);
            float cn = ff * cr[ns][idx] + ii * gg;
            cr[ns][idx] = cn;
            float hv = oo * ftanh(cn);
            p0 += hv * (float)w0h[idx];
            p1 += hv * (float)w1h[idx];
            pk.h[idx] = (f16)hv;
        }
        *(uint2*)(hb + ns * 4096 + hwo) = pk.u;
        p0 += __shfl_xor(p0, 16); p0 += __shfl_xor(p0, 32);
        p1 += __shfl_xor(p1, 16); p1 += __shfl_xor(p1, 32);
        if (q == 0) { pp[w][ns * 16 + cl][0] = p0; pp[w][ns * 16 + cl][1] = p1; }
    }
}

__device__ __forceinline__ void finalize(int g, int tdf, int tid, int s0,
        const float (*pp)[32][2], float lb0, float lb1,
        f16* xstage, float* __restrict__ out) {
    if (tid < 32) {
        float a0 = lb0, a1 = lb1;
        #pragma unroll
        for (int ww = 0; ww < 8; ++ww) { a0 += pp[ww][tid][0]; a1 += pp[ww][tid][1]; }
        const int s = g * 32 + tid;
        float2 o2; o2.x = a0; o2.y = a1;
        *(float2*)(out + (size_t)(s0 + s) * (PRED * 2) + tdf * 2) = o2;
        if (tdf < PRED - 1) {
            // dec_in(t+1) = [p0,p1,sc0,sc1,sc2,1,0,0]: slot49 row holds
            // [x0,x1,sc0,sc1,sc2,1,0,0] -> replace first dword only.
            uint4 row = *(const uint4*)(xstage + (49 * 64 + s) * 8);
            union { f16 h[2]; uint32_t u; } pk2;
            pk2.h[0] = (f16)a0; pk2.h[1] = (f16)a1;
            row.x = pk2.u;
            *(uint4*)(xstage + ((50 + g) * 64 + s) * 8) = row;
        }
    }
}

// 256 blocks x 512 threads, 64 samples/block as TWO pipeline groups of 32.
// Each phase: VALU-finish(group A, acc from prev phase) + MFMA(group B) --
// independent within the wave -> scheduler fills MFMA latency with the
// transcendental block. One barrier/phase; h single-buffered per group
// (write lands one barrier after all reads).
__global__ __launch_bounds__(512, 2)
void lstm_kernel(const float* __restrict__ x,
                 const float* __restrict__ eWih, const float* __restrict__ eWhh,
                 const float* __restrict__ ebih, const float* __restrict__ ebhh,
                 const float* __restrict__ dWih, const float* __restrict__ dWhh,
                 const float* __restrict__ dbih, const float* __restrict__ dbhh,
                 const float* __restrict__ linW, const float* __restrict__ linB,
                 float* __restrict__ out) {
    __shared__ __align__(16) unsigned char hstate[2 * 8192];        // 16 KB: [group][32 rows][256 B]
    __shared__ __align__(16) f16 xstage[52 * 64 * 8];               // 53.25 KB
    __shared__ float predpart[2][8][32][2];                         // 4 KB

    const int tid  = threadIdx.x;
    const int lane = tid & 63;
    const int w    = tid >> 6;
    const int q    = lane >> 4;
    const int cl   = lane & 15;
    const int s0   = blockIdx.x * 64;
    const int jb   = w * 16 + q * 4;
    const int fswz = (2 * (cl & 7)) | (cl >> 3);

    int hro[4];
    #pragma unroll
    for (int kc = 0; kc < 4; ++kc)
        hro[kc] = cl * 256 + (((kc * 4 + q) ^ fswz) & 15) * 16;
    const int physh = ((jb >> 3) ^ fswz) & 15;
    const int hwo   = cl * 256 + physh * 16 + (jb & 7) * 2;

    // ---- init: zero h state, stage all x as f16 rows ----
    {
        uint32_t* sp = (uint32_t*)hstate;
        #pragma unroll
        for (int r = 0; r < 8; ++r) sp[tid + r * 512] = 0u;
    }
    #pragma unroll
    for (int k = 0; k < 7; ++k) {
        int c = tid + k * 512;
        if (c < TT * 64) {
            int t = c >> 6, s = c & 63;
            const float* xr = x + (size_t)(s0 + s) * (TT * II) + t * II;
            union { f16 h[8]; uint4 u; } pk;
            pk.h[0] = (f16)xr[0]; pk.h[1] = (f16)xr[1]; pk.h[2] = (f16)xr[2];
            pk.h[3] = (f16)xr[3]; pk.h[4] = (f16)xr[4];
            pk.h[5] = (f16)1.f;  pk.h[6] = (f16)0.f;  pk.h[7] = (f16)0.f;
            *(uint4*)(xstage + (t * 64 + s) * 8) = pk.u;
        }
    }

    f16x8 wr[4][5];
    load_frags(eWih, eWhh, ebih, ebhh, w, q, cl, wr);

    float creg0[2][4], creg1[2][4];
    #pragma unroll
    for (int ns = 0; ns < 2; ++ns)
        #pragma unroll
        for (int i = 0; i < 4; ++i) { creg0[ns][i] = 0.f; creg1[ns][i] = 0.f; }

    f32x4 accA[4][2], accB[4][2];
    unsigned char* hb0 = hstate;
    unsigned char* hb1 = hstate + 8192;

    __syncthreads();

    // ===================== encoder pipeline =====================
    // k=0: MFMA(g0, t=0)
    mfma_group(accA, hb0, xstage + 0, wr, hro, cl);
    __syncthreads();
    #pragma unroll 1
    for (int j = 0; j < 49; ++j) {
        // odd: VALU(g0 -> h_{j+1}) ; MFMA(g1, t=j)
        valu_enc(accA, creg0, hb0, hwo);
        mfma_group(accB, hb1, xstage + (j * 64 + 32) * 8, wr, hro, cl);
        __syncthreads();
        // even: VALU(g1 -> h_{j+1}) ; MFMA(g0, t=j+1)
        valu_enc(accB, creg1, hb1, hwo);
        mfma_group(accA, hb0, xstage + ((j + 1) * 64) * 8, wr, hro, cl);
        __syncthreads();
    }
    // VALU(g0 -> h50) ; MFMA(g1, t=49)
    valu_enc(accA, creg0, hb0, hwo);
    mfma_group(accB, hb1, xstage + (49 * 64 + 32) * 8, wr, hro, cl);
    __syncthreads();
    // VALU(g1 -> h50)
    valu_enc(accB, creg1, hb1, hwo);
    __syncthreads();

    // ---- decoder weights + lin/bias ----
    load_frags(dWih, dWhh, dbih, dbhh, w, q, cl, wr);
    f16 w0h[4], w1h[4];
    #pragma unroll
    for (int idx = 0; idx < 4; ++idx) {
        w0h[idx] = (f16)linW[jb + idx];
        w1h[idx] = (f16)linW[128 + jb + idx];
    }
    const float lb0 = linB[0], lb1 = linB[1];

    // ===================== decoder pipeline =====================
    // m=0: MFMA(g0, td=0) from slot 49
    mfma_group(accA, hb0, xstage + (49 * 64) * 8, wr, hro, cl);
    __syncthreads();
    // m=1: VALU(g0, td=0) ; MFMA(g1, td=0)
    valu_dec(accA, creg0, hb0, hwo, w0h, w1h, predpart[0], w, q, cl);
    mfma_group(accB, hb1, xstage + (49 * 64 + 32) * 8, wr, hro, cl);
    __syncthreads();
    #pragma unroll 1
    for (int td = 1; td <= 11; ++td) {
        // finalize(g0,td-1); then VALU(g1,td-1) ; MFMA(g0,td) from slot 50
        finalize(0, td - 1, tid, s0, predpart[0], lb0, lb1, xstage, out);
        __syncthreads();
        valu_dec(accB, creg1, hb1, hwo, w0h, w1h, predpart[1], w, q, cl);
        mfma_group(accA, hb0, xstage + (50 * 64) * 8, wr, hro, cl);
        __syncthreads();
        // finalize(g1,td-1); then VALU(g0,td) ; MFMA(g1,td) from slot 51
        finalize(1, td - 1, tid, s0, predpart[1], lb0, lb1, xstage, out);
        __syncthreads();
        valu_dec(accA, creg0, hb0, hwo, w0h, w1h, predpart[0], w, q, cl);
        mfma_group(accB, hb1, xstage + (51 * 64 + 32) * 8, wr, hro, cl);
        __syncthreads();
    }
    // finalize(g0,11); VALU(g1,11); finalize(g1,11)
    finalize(0, 11, tid, s0, predpart[0], lb0, lb1, xstage, out);
    __syncthreads();
    valu_dec(accB, creg1, hb1, hwo, w0h, w1h, predpart[1], w, q, cl);
    __syncthreads();
    finalize(1, 11, tid, s0, predpart[1], lb0, lb1, xstage, out);
}

extern "C" void kernel_launch(void* const* d_in, const int* in_sizes, int n_in,
                              void* d_out, int out_size, void* d_ws, size_t ws_size,
                              hipStream_t stream) {
    (void)in_sizes; (void)n_in; (void)out_size; (void)d_ws; (void)ws_size;
    const float* x    = (const float*)d_in[0];
    const float* eWih = (const float*)d_in[1];
    const float* eWhh = (const float*)d_in[2];
    const float* ebih = (const float*)d_in[3];
    const float* ebhh = (const float*)d_in[4];
    const float* dWih = (const float*)d_in[5];
    const float* dWhh = (const float*)d_in[6];
    const float* dbih = (const float*)d_in[7];
    const float* dbhh = (const float*)d_in[8];
    const float* linW = (const float*)d_in[9];
    const float* linB = (const float*)d_in[10];

    lstm_kernel<<<256, 512, 0, stream>>>(x, eWih, eWhh, ebih, ebhh,
                                         dWih, dWhh, dbih, dbhh,
                                         linW, linB, (float*)d_out);
}